// Round 1
// baseline (2716.116 us; speedup 1.0000x reference)
//
#include <hip/hip_runtime.h>

constexpr int kB  = 512;
constexpr int kV  = 6890;
constexpr int kJ  = 24;
constexpr int kD  = kV * 3;   // 20670
constexpr int kNB = 10;
constexpr int kNF = 93;

// ---------------------------------------------------------------------------
// KA: batch-independent joint-regressor folding.
// JS[j][k][nb] = sum_v Jreg[j][v] * shapedirs[(v*3+k)*10+nb]
// JT[j][k]     = sum_v Jreg[j][v] * v_template[v*3+k]
// grid(72): one block per (j,k). block(256), wave butterfly + LDS reduce.
// ---------------------------------------------------------------------------
__global__ __launch_bounds__(256) void kA_js(
    const float* __restrict__ Jreg, const float* __restrict__ shapedirs,
    const float* __restrict__ v_template, float* __restrict__ js,
    float* __restrict__ jt) {
  int jk = blockIdx.x;
  int j = jk / 3, k = jk % 3;
  int tid = threadIdx.x;
  float acc[kNB];
  float accT = 0.f;
#pragma unroll
  for (int nb = 0; nb < kNB; ++nb) acc[nb] = 0.f;
  for (int v = tid; v < kV; v += 256) {
    float w = Jreg[(size_t)j * kV + v];
    const float* srow = shapedirs + (size_t)(v * 3 + k) * kNB;
    accT += w * v_template[v * 3 + k];
#pragma unroll
    for (int nb = 0; nb < kNB; ++nb) acc[nb] += w * srow[nb];
  }
#pragma unroll
  for (int nb = 0; nb < kNB; ++nb)
#pragma unroll
    for (int off = 32; off > 0; off >>= 1)
      acc[nb] += __shfl_down(acc[nb], off, 64);
#pragma unroll
  for (int off = 32; off > 0; off >>= 1) accT += __shfl_down(accT, off, 64);
  __shared__ float red[4][11];
  int wave = tid >> 6, lane = tid & 63;
  if (lane == 0) {
#pragma unroll
    for (int nb = 0; nb < kNB; ++nb) red[wave][nb] = acc[nb];
    red[wave][10] = accT;
  }
  __syncthreads();
  if (tid == 0) {
#pragma unroll
    for (int nb = 0; nb < kNB; ++nb)
      js[jk * kNB + nb] = red[0][nb] + red[1][nb] + red[2][nb] + red[3][nb];
    jt[jk] = red[0][10] + red[1][10] + red[2][10] + red[3][10];
  }
}

// ---------------------------------------------------------------------------
// KC: per-batch everything-small. Quat features -> pfT ([f][b] transposed),
// Rodrigues R (regs), Jp = JT + JS*betas (LDS), kinematic chain by tree
// level, G_skin, J_transformed. grid(kB), block(64) = 1 wave.
// ---------------------------------------------------------------------------
__global__ __launch_bounds__(64) void kC_batch(
    const float* __restrict__ pose, const float* __restrict__ betas,
    const float* __restrict__ trans, const float* __restrict__ js,
    const float* __restrict__ jt, float* __restrict__ pfT,
    float* __restrict__ Gskin, float* __restrict__ out_Jt) {
  const int parent[24] = {-1, 0, 0, 0, 1, 2, 3, 4, 5, 6, 7, 8,
                          9, 9, 9, 12, 13, 14, 16, 17, 18, 19, 20, 21};
  const int depth[24] = {0, 1, 1, 1, 2, 2, 2, 3, 3, 3, 4, 4,
                         4, 4, 4, 5, 5, 5, 6, 6, 7, 7, 8, 8};
  int b = blockIdx.x;
  int j = threadIdx.x;
  __shared__ float G[24][12];
  __shared__ float Jp_s[24][3];
  float R[9];
  if (j < 24) {
    float t0 = pose[b * 72 + 3 * j + 0];
    float t1 = pose[b * 72 + 3 * j + 1];
    float t2 = pose[b * 72 + 3 * j + 2];
    float a0 = t0 + 1e-8f, a1 = t1 + 1e-8f, a2 = t2 + 1e-8f;
    float angle = sqrtf(a0 * a0 + a1 * a1 + a2 * a2);
    float inv = 1.0f / angle;
    float h = 0.5f * angle;
    float c = cosf(h), s = sinf(h);
    float x = s * t0 * inv, y = s * t1 * inv, z = s * t2 * inv, w = c;
    if (j >= 1) {
      int f = 4 * (j - 1);
      pfT[(size_t)(f + 0) * kB + b] = x;
      pfT[(size_t)(f + 1) * kB + b] = y;
      pfT[(size_t)(f + 2) * kB + b] = z;
      pfT[(size_t)(f + 3) * kB + b] = c - 1.0f;
    } else {
      pfT[(size_t)92 * kB + b] = betas[b * kNB + 1];
    }
    float xx = x * x, yy = y * y, zz = z * z;
    float wx = w * x, wy = w * y, wz = w * z;
    float xy = x * y, xz = x * z, yz = y * z;
    R[0] = 1.f - 2.f * (yy + zz); R[1] = 2.f * (xy - wz); R[2] = 2.f * (xz + wy);
    R[3] = 2.f * (xy + wz); R[4] = 1.f - 2.f * (xx + zz); R[5] = 2.f * (yz - wx);
    R[6] = 2.f * (xz - wy); R[7] = 2.f * (yz + wx); R[8] = 1.f - 2.f * (xx + yy);
    float bet[kNB];
#pragma unroll
    for (int nb = 0; nb < kNB; ++nb) bet[nb] = betas[b * kNB + nb];
#pragma unroll
    for (int k = 0; k < 3; ++k) {
      float a = jt[j * 3 + k];
      const float* jr = js + (size_t)(j * 3 + k) * kNB;
#pragma unroll
      for (int nb = 0; nb < kNB; ++nb) a += jr[nb] * bet[nb];
      Jp_s[j][k] = a;
    }
  }
  __syncthreads();
  float tl[3];
  if (j < 24) {
    int p = parent[j];
#pragma unroll
    for (int k = 0; k < 3; ++k)
      tl[k] = (p >= 0) ? (Jp_s[j][k] - Jp_s[p][k]) : Jp_s[j][k];
    if (j == 0) {
#pragma unroll
      for (int r = 0; r < 3; ++r) {
        G[0][r * 4 + 0] = R[r * 3 + 0];
        G[0][r * 4 + 1] = R[r * 3 + 1];
        G[0][r * 4 + 2] = R[r * 3 + 2];
        G[0][r * 4 + 3] = tl[r];
      }
    }
  }
  __syncthreads();
  for (int lev = 1; lev <= 8; ++lev) {
    if (j < 24 && depth[j] == lev) {
      int p = parent[j];
      float nG[12];
#pragma unroll
      for (int r = 0; r < 3; ++r) {
        float g0 = G[p][r * 4 + 0], g1 = G[p][r * 4 + 1];
        float g2 = G[p][r * 4 + 2], g3 = G[p][r * 4 + 3];
        nG[r * 4 + 0] = g0 * R[0] + g1 * R[3] + g2 * R[6];
        nG[r * 4 + 1] = g0 * R[1] + g1 * R[4] + g2 * R[7];
        nG[r * 4 + 2] = g0 * R[2] + g1 * R[5] + g2 * R[8];
        nG[r * 4 + 3] = g0 * tl[0] + g1 * tl[1] + g2 * tl[2] + g3;
      }
#pragma unroll
      for (int e = 0; e < 12; ++e) G[j][e] = nG[e];
    }
    __syncthreads();
  }
  if (j < 24) {
    float tr[3];
#pragma unroll
    for (int k = 0; k < 3; ++k) tr[k] = trans[b * 3 + k];
#pragma unroll
    for (int k = 0; k < 3; ++k)
      out_Jt[b * 72 + j * 3 + k] = G[j][k * 4 + 3] + tr[k];
    float jp0 = Jp_s[j][0], jp1 = Jp_s[j][1], jp2 = Jp_s[j][2];
    float* gs = Gskin + b * 288 + j * 12;
#pragma unroll
    for (int r = 0; r < 3; ++r) {
      float t = G[j][r * 4 + 0] * jp0 + G[j][r * 4 + 1] * jp1 + G[j][r * 4 + 2] * jp2;
      gs[r * 4 + 0] = G[j][r * 4 + 0];
      gs[r * 4 + 1] = G[j][r * 4 + 1];
      gs[r * 4 + 2] = G[j][r * 4 + 2];
      gs[r * 4 + 3] = G[j][r * 4 + 3] - t;
    }
  }
}

// ---------------------------------------------------------------------------
// KF: fused blend + skin. Block = 192 threads = 64 vertices = 192 d-rows.
// Phase 1 (per-d): vshaped/vposed from register-resident dirs rows, with
//   betas/pfT tiles staged in LDS (broadcast reads, no scalar-load batches).
// Phase 2 (wave kRow x 64 vertices): T = w . Gskin from LDS-staged Gskin,
//   vposed handed off through LDS (no global round-trip).
// grid(108, 16): 16 y-blocks x 32 batches. LDS = 29.3 KB/block.
// ---------------------------------------------------------------------------
__global__ __launch_bounds__(192, 2) void kF_blend_skin(
    const float* __restrict__ shapedirs, const float* __restrict__ posedirs,
    const float* __restrict__ v_template, const float* __restrict__ betas,
    const float* __restrict__ pfT, const float* __restrict__ weights,
    const float* __restrict__ Gskin, const float* __restrict__ trans,
    float* __restrict__ out_vshaped, float* __restrict__ out_vposed,
    float* __restrict__ out_v) {
  __shared__ __align__(16) float pfT_s[93 * 32];   // [f][bcol]
  __shared__ float betas_s[32 * kNB];              // [bcol][nb]
  __shared__ __align__(16) float Gs_s[8 * 288];    // [t][j*12+r*4+e]
  __shared__ float vp_s[192][9];                   // [local d][t], pad 9

  const int tid = threadIdx.x;
  const int d0 = blockIdx.x * 192;
  const int v0 = blockIdx.x * 64;
  const int b0 = blockIdx.y * 32;
  const int d = d0 + tid;
  const bool act_d = d < kD;
  const int dl = act_d ? d : (kD - 1);
  const int kRow = tid >> 6;   // wave id = output row 0..2
  const int vloc = tid & 63;
  const bool act_v = (v0 + vloc) < kV;
  const int vl = act_v ? (v0 + vloc) : (kV - 1);

  // persistent per-thread data (amortized over 32 batches)
  float sd[kNB], pd[kNF], wreg[kJ];
#pragma unroll
  for (int k = 0; k < kNB; ++k) sd[k] = shapedirs[(size_t)dl * kNB + k];
#pragma unroll
  for (int f = 0; f < kNF; ++f) pd[f] = posedirs[(size_t)dl * kNF + f];
  float vt = v_template[dl];
#pragma unroll
  for (int j = 0; j < kJ; ++j) wreg[j] = weights[(size_t)vl * kJ + j];

  // stage pfT tile [93][32] and betas tile [32][10] once per block
  for (int i = tid; i < 93 * 32; i += 192) {
    int f = i >> 5, c = i & 31;
    pfT_s[i] = pfT[(size_t)f * kB + b0 + c];
  }
  for (int i = tid; i < 32 * kNB; i += 192)
    betas_s[i] = betas[(size_t)b0 * kNB + i];

#pragma unroll 1
  for (int bc = 0; bc < 4; ++bc) {
    // protects Gs_s/vp_s reuse from previous phase 2 (and initial staging)
    __syncthreads();

    // stage Gskin for this 8-batch group
    {
      const float* src = Gskin + (size_t)(b0 + bc * 8) * 288;
      for (int i = tid; i < 8 * 288; i += 192) Gs_s[i] = src[i];
    }

    // ---- phase 1: blend for 8 batches, this thread's d-row ----
    float as_[8], ap_[8];
#pragma unroll
    for (int t = 0; t < 8; ++t) {
      const float* be = betas_s + (bc * 8 + t) * kNB;
      float a = vt;
#pragma unroll
      for (int nb = 0; nb < kNB; ++nb) a += sd[nb] * be[nb];
      as_[t] = a;
      ap_[t] = a;
    }
    const float4* pf4 = (const float4*)pfT_s;  // row f = 8 float4s
#pragma unroll
    for (int f = 0; f < kNF; ++f) {
      float pdf = pd[f];
      float4 qa = pf4[f * 8 + bc * 2 + 0];
      float4 qb = pf4[f * 8 + bc * 2 + 1];
      ap_[0] += pdf * qa.x; ap_[1] += pdf * qa.y;
      ap_[2] += pdf * qa.z; ap_[3] += pdf * qa.w;
      ap_[4] += pdf * qb.x; ap_[5] += pdf * qb.y;
      ap_[6] += pdf * qb.z; ap_[7] += pdf * qb.w;
    }
#pragma unroll
    for (int t = 0; t < 8; ++t) {
      vp_s[tid][t] = ap_[t];
      if (act_d) {
        size_t idx = (size_t)(b0 + bc * 8 + t) * kD + d;
        out_vshaped[idx] = as_[t];
        out_vposed[idx] = ap_[t];
      }
    }
    __syncthreads();

    // ---- phase 2: skin 8 batches, this thread = (row kRow, vertex vloc) ----
#pragma unroll 1
    for (int t = 0; t < 8; ++t) {
      int b = b0 + bc * 8 + t;
      const float4* Gt = (const float4*)(Gs_s + t * 288);
      float T0 = 0.f, T1 = 0.f, T2 = 0.f, T3 = 0.f;
#pragma unroll
      for (int j = 0; j < kJ; ++j) {
        float4 g = Gt[j * 3 + kRow];  // G[j], row kRow, 4 floats (broadcast)
        T0 += wreg[j] * g.x; T1 += wreg[j] * g.y;
        T2 += wreg[j] * g.z; T3 += wreg[j] * g.w;
      }
      float q0 = vp_s[vloc * 3 + 0][t];
      float q1 = vp_s[vloc * 3 + 1][t];
      float q2 = vp_s[vloc * 3 + 2][t];
      float val = T0 * q0 + T1 * q1 + T2 * q2 + T3 + trans[b * 3 + kRow];
      if (act_v)
        out_v[(size_t)b * kD + (size_t)(v0 + vloc) * 3 + kRow] = val;
    }
  }
}

// ---------------------------------------------------------------------------
extern "C" void kernel_launch(void* const* d_in, const int* in_sizes, int n_in,
                              void* d_out, int out_size, void* d_ws,
                              size_t ws_size, hipStream_t stream) {
  const float* pose       = (const float*)d_in[0];
  const float* betas      = (const float*)d_in[1];
  const float* trans      = (const float*)d_in[2];
  const float* v_template = (const float*)d_in[3];
  const float* shapedirs  = (const float*)d_in[4];
  const float* posedirs   = (const float*)d_in[5];
  const float* Jreg       = (const float*)d_in[6];
  const float* weights    = (const float*)d_in[7];

  float* out = (float*)d_out;
  float* out_v       = out;
  float* out_vposed  = out + (size_t)kB * kD;
  float* out_vshaped = out + 2 * (size_t)kB * kD;
  float* out_Jt      = out + 3 * (size_t)kB * kD;

  float* wsf   = (float*)d_ws;
  float* pfT   = wsf;                   // kNF*kB
  float* Gskin = pfT + kNF * kB;        // kB*288
  float* js    = Gskin + kB * 288;      // 72*10
  float* jt    = js + 72 * kNB;         // 72

  hipLaunchKernelGGL(kA_js, dim3(72), dim3(256), 0, stream, Jreg, shapedirs,
                     v_template, js, jt);
  hipLaunchKernelGGL(kC_batch, dim3(kB), dim3(64), 0, stream, pose, betas,
                     trans, js, jt, pfT, Gskin, out_Jt);
  hipLaunchKernelGGL(kF_blend_skin, dim3(108, 16), dim3(192), 0, stream,
                     shapedirs, posedirs, v_template, betas, pfT, weights,
                     Gskin, trans, out_vshaped, out_vposed, out_v);
}

// Round 2
// 1808.268 us; speedup vs baseline: 1.5021x; 1.5021x over previous
//
#include <hip/hip_runtime.h>

constexpr int kB  = 512;
constexpr int kV  = 6890;
constexpr int kJ  = 24;
constexpr int kD  = kV * 3;   // 20670
constexpr int kNB = 10;
constexpr int kNF = 93;

// ---------------------------------------------------------------------------
// KA: batch-independent joint-regressor folding.
// JS[j][k][nb] = sum_v Jreg[j][v] * shapedirs[(v*3+k)*10+nb]
// JT[j][k]     = sum_v Jreg[j][v] * v_template[v*3+k]
// grid(72): one block per (j,k). block(256), wave butterfly + LDS reduce.
// ---------------------------------------------------------------------------
__global__ __launch_bounds__(256) void kA_js(
    const float* __restrict__ Jreg, const float* __restrict__ shapedirs,
    const float* __restrict__ v_template, float* __restrict__ js,
    float* __restrict__ jt) {
  int jk = blockIdx.x;
  int j = jk / 3, k = jk % 3;
  int tid = threadIdx.x;
  float acc[kNB];
  float accT = 0.f;
#pragma unroll
  for (int nb = 0; nb < kNB; ++nb) acc[nb] = 0.f;
  for (int v = tid; v < kV; v += 256) {
    float w = Jreg[(size_t)j * kV + v];
    const float* srow = shapedirs + (size_t)(v * 3 + k) * kNB;
    accT += w * v_template[v * 3 + k];
#pragma unroll
    for (int nb = 0; nb < kNB; ++nb) acc[nb] += w * srow[nb];
  }
#pragma unroll
  for (int nb = 0; nb < kNB; ++nb)
#pragma unroll
    for (int off = 32; off > 0; off >>= 1)
      acc[nb] += __shfl_down(acc[nb], off, 64);
#pragma unroll
  for (int off = 32; off > 0; off >>= 1) accT += __shfl_down(accT, off, 64);
  __shared__ float red[4][11];
  int wave = tid >> 6, lane = tid & 63;
  if (lane == 0) {
#pragma unroll
    for (int nb = 0; nb < kNB; ++nb) red[wave][nb] = acc[nb];
    red[wave][10] = accT;
  }
  __syncthreads();
  if (tid == 0) {
#pragma unroll
    for (int nb = 0; nb < kNB; ++nb)
      js[jk * kNB + nb] = red[0][nb] + red[1][nb] + red[2][nb] + red[3][nb];
    jt[jk] = red[0][10] + red[1][10] + red[2][10] + red[3][10];
  }
}

// ---------------------------------------------------------------------------
// KC: per-batch everything-small. Quat features -> pfT ([f][b] transposed),
// Rodrigues R (regs), Jp = JT + JS*betas (LDS), kinematic chain by tree
// level, G_skin, J_transformed. grid(kB), block(64) = 1 wave.
// ---------------------------------------------------------------------------
__global__ __launch_bounds__(64) void kC_batch(
    const float* __restrict__ pose, const float* __restrict__ betas,
    const float* __restrict__ trans, const float* __restrict__ js,
    const float* __restrict__ jt, float* __restrict__ pfT,
    float* __restrict__ Gskin, float* __restrict__ out_Jt) {
  const int parent[24] = {-1, 0, 0, 0, 1, 2, 3, 4, 5, 6, 7, 8,
                          9, 9, 9, 12, 13, 14, 16, 17, 18, 19, 20, 21};
  const int depth[24] = {0, 1, 1, 1, 2, 2, 2, 3, 3, 3, 4, 4,
                         4, 4, 4, 5, 5, 5, 6, 6, 7, 7, 8, 8};
  int b = blockIdx.x;
  int j = threadIdx.x;
  __shared__ float G[24][12];
  __shared__ float Jp_s[24][3];
  float R[9];
  if (j < 24) {
    float t0 = pose[b * 72 + 3 * j + 0];
    float t1 = pose[b * 72 + 3 * j + 1];
    float t2 = pose[b * 72 + 3 * j + 2];
    float a0 = t0 + 1e-8f, a1 = t1 + 1e-8f, a2 = t2 + 1e-8f;
    float angle = sqrtf(a0 * a0 + a1 * a1 + a2 * a2);
    float inv = 1.0f / angle;
    float h = 0.5f * angle;
    float c = cosf(h), s = sinf(h);
    float x = s * t0 * inv, y = s * t1 * inv, z = s * t2 * inv, w = c;
    if (j >= 1) {
      int f = 4 * (j - 1);
      pfT[(size_t)(f + 0) * kB + b] = x;
      pfT[(size_t)(f + 1) * kB + b] = y;
      pfT[(size_t)(f + 2) * kB + b] = z;
      pfT[(size_t)(f + 3) * kB + b] = c - 1.0f;
    } else {
      pfT[(size_t)92 * kB + b] = betas[b * kNB + 1];
    }
    float xx = x * x, yy = y * y, zz = z * z;
    float wx = w * x, wy = w * y, wz = w * z;
    float xy = x * y, xz = x * z, yz = y * z;
    R[0] = 1.f - 2.f * (yy + zz); R[1] = 2.f * (xy - wz); R[2] = 2.f * (xz + wy);
    R[3] = 2.f * (xy + wz); R[4] = 1.f - 2.f * (xx + zz); R[5] = 2.f * (yz - wx);
    R[6] = 2.f * (xz - wy); R[7] = 2.f * (yz + wx); R[8] = 1.f - 2.f * (xx + yy);
    float bet[kNB];
#pragma unroll
    for (int nb = 0; nb < kNB; ++nb) bet[nb] = betas[b * kNB + nb];
#pragma unroll
    for (int k = 0; k < 3; ++k) {
      float a = jt[j * 3 + k];
      const float* jr = js + (size_t)(j * 3 + k) * kNB;
#pragma unroll
      for (int nb = 0; nb < kNB; ++nb) a += jr[nb] * bet[nb];
      Jp_s[j][k] = a;
    }
  }
  __syncthreads();
  float tl[3];
  if (j < 24) {
    int p = parent[j];
#pragma unroll
    for (int k = 0; k < 3; ++k)
      tl[k] = (p >= 0) ? (Jp_s[j][k] - Jp_s[p][k]) : Jp_s[j][k];
    if (j == 0) {
#pragma unroll
      for (int r = 0; r < 3; ++r) {
        G[0][r * 4 + 0] = R[r * 3 + 0];
        G[0][r * 4 + 1] = R[r * 3 + 1];
        G[0][r * 4 + 2] = R[r * 3 + 2];
        G[0][r * 4 + 3] = tl[r];
      }
    }
  }
  __syncthreads();
  for (int lev = 1; lev <= 8; ++lev) {
    if (j < 24 && depth[j] == lev) {
      int p = parent[j];
      float nG[12];
#pragma unroll
      for (int r = 0; r < 3; ++r) {
        float g0 = G[p][r * 4 + 0], g1 = G[p][r * 4 + 1];
        float g2 = G[p][r * 4 + 2], g3 = G[p][r * 4 + 3];
        nG[r * 4 + 0] = g0 * R[0] + g1 * R[3] + g2 * R[6];
        nG[r * 4 + 1] = g0 * R[1] + g1 * R[4] + g2 * R[7];
        nG[r * 4 + 2] = g0 * R[2] + g1 * R[5] + g2 * R[8];
        nG[r * 4 + 3] = g0 * tl[0] + g1 * tl[1] + g2 * tl[2] + g3;
      }
#pragma unroll
      for (int e = 0; e < 12; ++e) G[j][e] = nG[e];
    }
    __syncthreads();
  }
  if (j < 24) {
    float tr[3];
#pragma unroll
    for (int k = 0; k < 3; ++k) tr[k] = trans[b * 3 + k];
#pragma unroll
    for (int k = 0; k < 3; ++k)
      out_Jt[b * 72 + j * 3 + k] = G[j][k * 4 + 3] + tr[k];
    float jp0 = Jp_s[j][0], jp1 = Jp_s[j][1], jp2 = Jp_s[j][2];
    float* gs = Gskin + b * 288 + j * 12;
#pragma unroll
    for (int r = 0; r < 3; ++r) {
      float t = G[j][r * 4 + 0] * jp0 + G[j][r * 4 + 1] * jp1 + G[j][r * 4 + 2] * jp2;
      gs[r * 4 + 0] = G[j][r * 4 + 0];
      gs[r * 4 + 1] = G[j][r * 4 + 1];
      gs[r * 4 + 2] = G[j][r * 4 + 2];
      gs[r * 4 + 3] = G[j][r * 4 + 3] - t;
    }
  }
}

// ---------------------------------------------------------------------------
// KF: fused blend + skin. Block = 192 threads = 64 vertices = 192 d-rows.
// Phase 1 (per-d): vshaped/vposed from register-resident dirs rows, with
//   betas/pfT tiles staged in LDS (broadcast reads, no scalar-load batches).
// Phase 2 (wave kRow x 64 vertices): T = w . Gskin from LDS-staged Gskin,
//   vposed handed off through LDS (no global round-trip).
// grid(108, 16): 16 y-blocks x 32 batches. LDS = 29.3 KB/block.
// NOTE: plain __launch_bounds__(192) — a min-waves clause of 2 capped VGPRs
// at 128 and spilled pd[93] to scratch (6.4 GB/dispatch, 10x slowdown).
// ---------------------------------------------------------------------------
__global__ __launch_bounds__(192) void kF_blend_skin(
    const float* __restrict__ shapedirs, const float* __restrict__ posedirs,
    const float* __restrict__ v_template, const float* __restrict__ betas,
    const float* __restrict__ pfT, const float* __restrict__ weights,
    const float* __restrict__ Gskin, const float* __restrict__ trans,
    float* __restrict__ out_vshaped, float* __restrict__ out_vposed,
    float* __restrict__ out_v) {
  __shared__ __align__(16) float pfT_s[93 * 32];   // [f][bcol]
  __shared__ float betas_s[32 * kNB];              // [bcol][nb]
  __shared__ __align__(16) float Gs_s[8 * 288];    // [t][j*12+r*4+e]
  __shared__ float vp_s[192][9];                   // [local d][t], pad 9

  const int tid = threadIdx.x;
  const int d0 = blockIdx.x * 192;
  const int v0 = blockIdx.x * 64;
  const int b0 = blockIdx.y * 32;
  const int d = d0 + tid;
  const bool act_d = d < kD;
  const int dl = act_d ? d : (kD - 1);
  const int kRow = tid >> 6;   // wave id = output row 0..2
  const int vloc = tid & 63;
  const bool act_v = (v0 + vloc) < kV;
  const int vl = act_v ? (v0 + vloc) : (kV - 1);

  // persistent per-thread data (amortized over 32 batches)
  float sd[kNB], pd[kNF], wreg[kJ];
#pragma unroll
  for (int k = 0; k < kNB; ++k) sd[k] = shapedirs[(size_t)dl * kNB + k];
#pragma unroll
  for (int f = 0; f < kNF; ++f) pd[f] = posedirs[(size_t)dl * kNF + f];
  float vt = v_template[dl];
#pragma unroll
  for (int j = 0; j < kJ; ++j) wreg[j] = weights[(size_t)vl * kJ + j];

  // stage pfT tile [93][32] and betas tile [32][10] once per block
  for (int i = tid; i < 93 * 32; i += 192) {
    int f = i >> 5, c = i & 31;
    pfT_s[i] = pfT[(size_t)f * kB + b0 + c];
  }
  for (int i = tid; i < 32 * kNB; i += 192)
    betas_s[i] = betas[(size_t)b0 * kNB + i];

#pragma unroll 1
  for (int bc = 0; bc < 4; ++bc) {
    // protects Gs_s/vp_s reuse from previous phase 2 (and initial staging)
    __syncthreads();

    // stage Gskin for this 8-batch group
    {
      const float* src = Gskin + (size_t)(b0 + bc * 8) * 288;
      for (int i = tid; i < 8 * 288; i += 192) Gs_s[i] = src[i];
    }

    // ---- phase 1: blend for 8 batches, this thread's d-row ----
    float as_[8], ap_[8];
#pragma unroll
    for (int t = 0; t < 8; ++t) {
      const float* be = betas_s + (bc * 8 + t) * kNB;
      float a = vt;
#pragma unroll
      for (int nb = 0; nb < kNB; ++nb) a += sd[nb] * be[nb];
      as_[t] = a;
      ap_[t] = a;
    }
    const float4* pf4 = (const float4*)pfT_s;  // row f = 8 float4s
#pragma unroll
    for (int f = 0; f < kNF; ++f) {
      float pdf = pd[f];
      float4 qa = pf4[f * 8 + bc * 2 + 0];
      float4 qb = pf4[f * 8 + bc * 2 + 1];
      ap_[0] += pdf * qa.x; ap_[1] += pdf * qa.y;
      ap_[2] += pdf * qa.z; ap_[3] += pdf * qa.w;
      ap_[4] += pdf * qb.x; ap_[5] += pdf * qb.y;
      ap_[6] += pdf * qb.z; ap_[7] += pdf * qb.w;
    }
#pragma unroll
    for (int t = 0; t < 8; ++t) {
      vp_s[tid][t] = ap_[t];
      if (act_d) {
        size_t idx = (size_t)(b0 + bc * 8 + t) * kD + d;
        out_vshaped[idx] = as_[t];
        out_vposed[idx] = ap_[t];
      }
    }
    __syncthreads();

    // ---- phase 2: skin 8 batches, this thread = (row kRow, vertex vloc) ----
#pragma unroll 1
    for (int t = 0; t < 8; ++t) {
      int b = b0 + bc * 8 + t;
      const float4* Gt = (const float4*)(Gs_s + t * 288);
      float T0 = 0.f, T1 = 0.f, T2 = 0.f, T3 = 0.f;
#pragma unroll
      for (int j = 0; j < kJ; ++j) {
        float4 g = Gt[j * 3 + kRow];  // G[j], row kRow, 4 floats (broadcast)
        T0 += wreg[j] * g.x; T1 += wreg[j] * g.y;
        T2 += wreg[j] * g.z; T3 += wreg[j] * g.w;
      }
      float q0 = vp_s[vloc * 3 + 0][t];
      float q1 = vp_s[vloc * 3 + 1][t];
      float q2 = vp_s[vloc * 3 + 2][t];
      float val = T0 * q0 + T1 * q1 + T2 * q2 + T3 + trans[b * 3 + kRow];
      if (act_v)
        out_v[(size_t)b * kD + (size_t)(v0 + vloc) * 3 + kRow] = val;
    }
  }
}

// ---------------------------------------------------------------------------
extern "C" void kernel_launch(void* const* d_in, const int* in_sizes, int n_in,
                              void* d_out, int out_size, void* d_ws,
                              size_t ws_size, hipStream_t stream) {
  const float* pose       = (const float*)d_in[0];
  const float* betas      = (const float*)d_in[1];
  const float* trans      = (const float*)d_in[2];
  const float* v_template = (const float*)d_in[3];
  const float* shapedirs  = (const float*)d_in[4];
  const float* posedirs   = (const float*)d_in[5];
  const float* Jreg       = (const float*)d_in[6];
  const float* weights    = (const float*)d_in[7];

  float* out = (float*)d_out;
  float* out_v       = out;
  float* out_vposed  = out + (size_t)kB * kD;
  float* out_vshaped = out + 2 * (size_t)kB * kD;
  float* out_Jt      = out + 3 * (size_t)kB * kD;

  float* wsf   = (float*)d_ws;
  float* pfT   = wsf;                   // kNF*kB
  float* Gskin = pfT + kNF * kB;        // kB*288
  float* js    = Gskin + kB * 288;      // 72*10
  float* jt    = js + 72 * kNB;         // 72

  hipLaunchKernelGGL(kA_js, dim3(72), dim3(256), 0, stream, Jreg, shapedirs,
                     v_template, js, jt);
  hipLaunchKernelGGL(kC_batch, dim3(kB), dim3(64), 0, stream, pose, betas,
                     trans, js, jt, pfT, Gskin, out_Jt);
  hipLaunchKernelGGL(kF_blend_skin, dim3(108, 16), dim3(192), 0, stream,
                     shapedirs, posedirs, v_template, betas, pfT, weights,
                     Gskin, trans, out_vshaped, out_vposed, out_v);
}

// Round 3
// 396.629 us; speedup vs baseline: 6.8480x; 4.5591x over previous
//
#include <hip/hip_runtime.h>

constexpr int kB  = 512;
constexpr int kV  = 6890;
constexpr int kJ  = 24;
constexpr int kD  = kV * 3;   // 20670
constexpr int kNB = 10;
constexpr int kNF = 93;

// ---------------------------------------------------------------------------
// KA: batch-independent joint-regressor folding.
// JS[j][k][nb] = sum_v Jreg[j][v] * shapedirs[(v*3+k)*10+nb]
// JT[j][k]     = sum_v Jreg[j][v] * v_template[v*3+k]
// grid(72): one block per (j,k). block(256), wave butterfly + LDS reduce.
// ---------------------------------------------------------------------------
__global__ __launch_bounds__(256) void kA_js(
    const float* __restrict__ Jreg, const float* __restrict__ shapedirs,
    const float* __restrict__ v_template, float* __restrict__ js,
    float* __restrict__ jt) {
  int jk = blockIdx.x;
  int j = jk / 3, k = jk % 3;
  int tid = threadIdx.x;
  float acc[kNB];
  float accT = 0.f;
#pragma unroll
  for (int nb = 0; nb < kNB; ++nb) acc[nb] = 0.f;
  for (int v = tid; v < kV; v += 256) {
    float w = Jreg[(size_t)j * kV + v];
    const float* srow = shapedirs + (size_t)(v * 3 + k) * kNB;
    accT += w * v_template[v * 3 + k];
#pragma unroll
    for (int nb = 0; nb < kNB; ++nb) acc[nb] += w * srow[nb];
  }
#pragma unroll
  for (int nb = 0; nb < kNB; ++nb)
#pragma unroll
    for (int off = 32; off > 0; off >>= 1)
      acc[nb] += __shfl_down(acc[nb], off, 64);
#pragma unroll
  for (int off = 32; off > 0; off >>= 1) accT += __shfl_down(accT, off, 64);
  __shared__ float red[4][11];
  int wave = tid >> 6, lane = tid & 63;
  if (lane == 0) {
#pragma unroll
    for (int nb = 0; nb < kNB; ++nb) red[wave][nb] = acc[nb];
    red[wave][10] = accT;
  }
  __syncthreads();
  if (tid == 0) {
#pragma unroll
    for (int nb = 0; nb < kNB; ++nb)
      js[jk * kNB + nb] = red[0][nb] + red[1][nb] + red[2][nb] + red[3][nb];
    jt[jk] = red[0][10] + red[1][10] + red[2][10] + red[3][10];
  }
}

// ---------------------------------------------------------------------------
// KC: per-batch everything-small. Quat features -> pfT ([f][b] transposed),
// Rodrigues R (regs), Jp = JT + JS*betas (LDS), kinematic chain by tree
// level, G_skin, J_transformed. grid(kB), block(64) = 1 wave.
// ---------------------------------------------------------------------------
__global__ __launch_bounds__(64) void kC_batch(
    const float* __restrict__ pose, const float* __restrict__ betas,
    const float* __restrict__ trans, const float* __restrict__ js,
    const float* __restrict__ jt, float* __restrict__ pfT,
    float* __restrict__ Gskin, float* __restrict__ out_Jt) {
  const int parent[24] = {-1, 0, 0, 0, 1, 2, 3, 4, 5, 6, 7, 8,
                          9, 9, 9, 12, 13, 14, 16, 17, 18, 19, 20, 21};
  const int depth[24] = {0, 1, 1, 1, 2, 2, 2, 3, 3, 3, 4, 4,
                         4, 4, 4, 5, 5, 5, 6, 6, 7, 7, 8, 8};
  int b = blockIdx.x;
  int j = threadIdx.x;
  __shared__ float G[24][12];
  __shared__ float Jp_s[24][3];
  float R[9];
  if (j < 24) {
    float t0 = pose[b * 72 + 3 * j + 0];
    float t1 = pose[b * 72 + 3 * j + 1];
    float t2 = pose[b * 72 + 3 * j + 2];
    float a0 = t0 + 1e-8f, a1 = t1 + 1e-8f, a2 = t2 + 1e-8f;
    float angle = sqrtf(a0 * a0 + a1 * a1 + a2 * a2);
    float inv = 1.0f / angle;
    float h = 0.5f * angle;
    float c = cosf(h), s = sinf(h);
    float x = s * t0 * inv, y = s * t1 * inv, z = s * t2 * inv, w = c;
    if (j >= 1) {
      int f = 4 * (j - 1);
      pfT[(size_t)(f + 0) * kB + b] = x;
      pfT[(size_t)(f + 1) * kB + b] = y;
      pfT[(size_t)(f + 2) * kB + b] = z;
      pfT[(size_t)(f + 3) * kB + b] = c - 1.0f;
    } else {
      pfT[(size_t)92 * kB + b] = betas[b * kNB + 1];
    }
    float xx = x * x, yy = y * y, zz = z * z;
    float wx = w * x, wy = w * y, wz = w * z;
    float xy = x * y, xz = x * z, yz = y * z;
    R[0] = 1.f - 2.f * (yy + zz); R[1] = 2.f * (xy - wz); R[2] = 2.f * (xz + wy);
    R[3] = 2.f * (xy + wz); R[4] = 1.f - 2.f * (xx + zz); R[5] = 2.f * (yz - wx);
    R[6] = 2.f * (xz - wy); R[7] = 2.f * (yz + wx); R[8] = 1.f - 2.f * (xx + yy);
    float bet[kNB];
#pragma unroll
    for (int nb = 0; nb < kNB; ++nb) bet[nb] = betas[b * kNB + nb];
#pragma unroll
    for (int k = 0; k < 3; ++k) {
      float a = jt[j * 3 + k];
      const float* jr = js + (size_t)(j * 3 + k) * kNB;
#pragma unroll
      for (int nb = 0; nb < kNB; ++nb) a += jr[nb] * bet[nb];
      Jp_s[j][k] = a;
    }
  }
  __syncthreads();
  float tl[3];
  if (j < 24) {
    int p = parent[j];
#pragma unroll
    for (int k = 0; k < 3; ++k)
      tl[k] = (p >= 0) ? (Jp_s[j][k] - Jp_s[p][k]) : Jp_s[j][k];
    if (j == 0) {
#pragma unroll
      for (int r = 0; r < 3; ++r) {
        G[0][r * 4 + 0] = R[r * 3 + 0];
        G[0][r * 4 + 1] = R[r * 3 + 1];
        G[0][r * 4 + 2] = R[r * 3 + 2];
        G[0][r * 4 + 3] = tl[r];
      }
    }
  }
  __syncthreads();
  for (int lev = 1; lev <= 8; ++lev) {
    if (j < 24 && depth[j] == lev) {
      int p = parent[j];
      float nG[12];
#pragma unroll
      for (int r = 0; r < 3; ++r) {
        float g0 = G[p][r * 4 + 0], g1 = G[p][r * 4 + 1];
        float g2 = G[p][r * 4 + 2], g3 = G[p][r * 4 + 3];
        nG[r * 4 + 0] = g0 * R[0] + g1 * R[3] + g2 * R[6];
        nG[r * 4 + 1] = g0 * R[1] + g1 * R[4] + g2 * R[7];
        nG[r * 4 + 2] = g0 * R[2] + g1 * R[5] + g2 * R[8];
        nG[r * 4 + 3] = g0 * tl[0] + g1 * tl[1] + g2 * tl[2] + g3;
      }
#pragma unroll
      for (int e = 0; e < 12; ++e) G[j][e] = nG[e];
    }
    __syncthreads();
  }
  if (j < 24) {
    float tr[3];
#pragma unroll
    for (int k = 0; k < 3; ++k) tr[k] = trans[b * 3 + k];
#pragma unroll
    for (int k = 0; k < 3; ++k)
      out_Jt[b * 72 + j * 3 + k] = G[j][k * 4 + 3] + tr[k];
    float jp0 = Jp_s[j][0], jp1 = Jp_s[j][1], jp2 = Jp_s[j][2];
    float* gs = Gskin + b * 288 + j * 12;
#pragma unroll
    for (int r = 0; r < 3; ++r) {
      float t = G[j][r * 4 + 0] * jp0 + G[j][r * 4 + 1] * jp1 + G[j][r * 4 + 2] * jp2;
      gs[r * 4 + 0] = G[j][r * 4 + 0];
      gs[r * 4 + 1] = G[j][r * 4 + 1];
      gs[r * 4 + 2] = G[j][r * 4 + 2];
      gs[r * 4 + 3] = G[j][r * 4 + 3] - t;
    }
  }
}

// ---------------------------------------------------------------------------
// KF: fused blend + skin. Block = 192 threads = 64 vertices = 192 d-rows.
// Phase 1 (per-d): vshaped/vposed from register-resident dirs rows, with
//   betas/pfT tiles staged in LDS (broadcast reads).
// Phase 2 (wave kRow x 64 vertices): T = w . Gskin from LDS-staged Gskin,
//   vposed handed off through LDS (no global round-trip).
// grid(108, 16): 16 y-blocks x 32 batches. LDS = 29.3 KB/block.
// NOTES:
//  - plain __launch_bounds__(192): a min-waves clause of 2 capped VGPRs at
//    128 and spilled pd[93] (6.4 GB scratch traffic).
//  - f-loop MUST be #pragma unroll 4: full unroll lets the scheduler hoist
//    ~186 float4 ds_reads (VGPR-only destinations) -> transient pressure
//    >256 -> accumulator spill (3.2 GB scratch traffic, round 2).
//  - out_vshaped stored before the f-loop so as_[8] dies early.
// ---------------------------------------------------------------------------
__global__ __launch_bounds__(192) void kF_blend_skin(
    const float* __restrict__ shapedirs, const float* __restrict__ posedirs,
    const float* __restrict__ v_template, const float* __restrict__ betas,
    const float* __restrict__ pfT, const float* __restrict__ weights,
    const float* __restrict__ Gskin, const float* __restrict__ trans,
    float* __restrict__ out_vshaped, float* __restrict__ out_vposed,
    float* __restrict__ out_v) {
  __shared__ __align__(16) float pfT_s[93 * 32];   // [f][bcol]
  __shared__ float betas_s[32 * kNB];              // [bcol][nb]
  __shared__ __align__(16) float Gs_s[8 * 288];    // [t][j*12+r*4+e]
  __shared__ float vp_s[192][9];                   // [local d][t], pad 9

  const int tid = threadIdx.x;
  const int d0 = blockIdx.x * 192;
  const int v0 = blockIdx.x * 64;
  const int b0 = blockIdx.y * 32;
  const int d = d0 + tid;
  const bool act_d = d < kD;
  const int dl = act_d ? d : (kD - 1);
  const int kRow = tid >> 6;   // wave id = output row 0..2
  const int vloc = tid & 63;
  const bool act_v = (v0 + vloc) < kV;
  const int vl = act_v ? (v0 + vloc) : (kV - 1);

  // persistent per-thread data (amortized over 32 batches)
  float sd[kNB], pd[kNF], wreg[kJ];
#pragma unroll
  for (int k = 0; k < kNB; ++k) sd[k] = shapedirs[(size_t)dl * kNB + k];
#pragma unroll
  for (int f = 0; f < kNF; ++f) pd[f] = posedirs[(size_t)dl * kNF + f];
  float vt = v_template[dl];
#pragma unroll
  for (int j = 0; j < kJ; ++j) wreg[j] = weights[(size_t)vl * kJ + j];

  // stage pfT tile [93][32] and betas tile [32][10] once per block
  for (int i = tid; i < 93 * 32; i += 192) {
    int f = i >> 5, c = i & 31;
    pfT_s[i] = pfT[(size_t)f * kB + b0 + c];
  }
  for (int i = tid; i < 32 * kNB; i += 192)
    betas_s[i] = betas[(size_t)b0 * kNB + i];

#pragma unroll 1
  for (int bc = 0; bc < 4; ++bc) {
    // protects Gs_s/vp_s reuse from previous phase 2 (and initial staging)
    __syncthreads();

    // stage Gskin for this 8-batch group
    {
      const float* src = Gskin + (size_t)(b0 + bc * 8) * 288;
      for (int i = tid; i < 8 * 288; i += 192) Gs_s[i] = src[i];
    }

    // ---- phase 1: blend for 8 batches, this thread's d-row ----
    float ap_[8];
#pragma unroll
    for (int t = 0; t < 8; ++t) {
      const float* be = betas_s + (bc * 8 + t) * kNB;
      float a = vt;
#pragma unroll
      for (int nb = 0; nb < kNB; ++nb) a += sd[nb] * be[nb];
      ap_[t] = a;
      if (act_d)
        out_vshaped[(size_t)(b0 + bc * 8 + t) * kD + d] = a;  // as_ dies here
    }
    const float4* pf4 = (const float4*)pfT_s;  // row f = 8 float4s
#pragma unroll 4
    for (int f = 0; f < kNF; ++f) {
      float pdf = pd[f];
      float4 qa = pf4[f * 8 + bc * 2 + 0];
      float4 qb = pf4[f * 8 + bc * 2 + 1];
      ap_[0] += pdf * qa.x; ap_[1] += pdf * qa.y;
      ap_[2] += pdf * qa.z; ap_[3] += pdf * qa.w;
      ap_[4] += pdf * qb.x; ap_[5] += pdf * qb.y;
      ap_[6] += pdf * qb.z; ap_[7] += pdf * qb.w;
    }
#pragma unroll
    for (int t = 0; t < 8; ++t) {
      vp_s[tid][t] = ap_[t];
      if (act_d)
        out_vposed[(size_t)(b0 + bc * 8 + t) * kD + d] = ap_[t];
    }
    __syncthreads();

    // ---- phase 2: skin 8 batches, this thread = (row kRow, vertex vloc) ----
#pragma unroll 1
    for (int t = 0; t < 8; ++t) {
      int b = b0 + bc * 8 + t;
      const float4* Gt = (const float4*)(Gs_s + t * 288);
      float T0 = 0.f, T1 = 0.f, T2 = 0.f, T3 = 0.f;
#pragma unroll
      for (int j = 0; j < kJ; ++j) {
        float4 g = Gt[j * 3 + kRow];  // G[j], row kRow, 4 floats (broadcast)
        T0 += wreg[j] * g.x; T1 += wreg[j] * g.y;
        T2 += wreg[j] * g.z; T3 += wreg[j] * g.w;
      }
      float q0 = vp_s[vloc * 3 + 0][t];
      float q1 = vp_s[vloc * 3 + 1][t];
      float q2 = vp_s[vloc * 3 + 2][t];
      float val = T0 * q0 + T1 * q1 + T2 * q2 + T3 + trans[b * 3 + kRow];
      if (act_v)
        out_v[(size_t)b * kD + (size_t)(v0 + vloc) * 3 + kRow] = val;
    }
  }
}

// ---------------------------------------------------------------------------
extern "C" void kernel_launch(void* const* d_in, const int* in_sizes, int n_in,
                              void* d_out, int out_size, void* d_ws,
                              size_t ws_size, hipStream_t stream) {
  const float* pose       = (const float*)d_in[0];
  const float* betas      = (const float*)d_in[1];
  const float* trans      = (const float*)d_in[2];
  const float* v_template = (const float*)d_in[3];
  const float* shapedirs  = (const float*)d_in[4];
  const float* posedirs   = (const float*)d_in[5];
  const float* Jreg       = (const float*)d_in[6];
  const float* weights    = (const float*)d_in[7];

  float* out = (float*)d_out;
  float* out_v       = out;
  float* out_vposed  = out + (size_t)kB * kD;
  float* out_vshaped = out + 2 * (size_t)kB * kD;
  float* out_Jt      = out + 3 * (size_t)kB * kD;

  float* wsf   = (float*)d_ws;
  float* pfT   = wsf;                   // kNF*kB
  float* Gskin = pfT + kNF * kB;        // kB*288
  float* js    = Gskin + kB * 288;      // 72*10
  float* jt    = js + 72 * kNB;         // 72

  hipLaunchKernelGGL(kA_js, dim3(72), dim3(256), 0, stream, Jreg, shapedirs,
                     v_template, js, jt);
  hipLaunchKernelGGL(kC_batch, dim3(kB), dim3(64), 0, stream, pose, betas,
                     trans, js, jt, pfT, Gskin, out_Jt);
  hipLaunchKernelGGL(kF_blend_skin, dim3(108, 16), dim3(192), 0, stream,
                     shapedirs, posedirs, v_template, betas, pfT, weights,
                     Gskin, trans, out_vshaped, out_vposed, out_v);
}